// Round 2
// baseline (1537.389 us; speedup 1.0000x reference)
//
#include <hip/hip_runtime.h>

typedef __attribute__((ext_vector_type(8))) short bf16x8;
typedef __attribute__((ext_vector_type(4))) float f32x4;

__device__ __forceinline__ unsigned short f2bf(float x) {
  union { float f; unsigned u; } v; v.f = x;
  return (unsigned short)((v.u + 0x7fffu + ((v.u >> 16) & 1u)) >> 16);
}
__device__ __forceinline__ float bf2f(unsigned short h) {
  union { unsigned u; float f; } v; v.u = ((unsigned)h) << 16; return v.f;
}

// ================= CSR build: two-level counting sort by dst =================
// Bucket = dst >> 8 (256 nodes per bucket). Record = (dst&255)<<17 | src (25 bits).

// -- bucket histogram (LDS sub-hist, then merge) --
__global__ __launch_bounds__(256) void bhist_k(const int* __restrict__ dst,
                                               int* __restrict__ bcnt, int E, int B) {
  __shared__ int h[512];
  for (int i = threadIdx.x; i < B; i += 256) h[i] = 0;
  __syncthreads();
  for (int e = blockIdx.x * 256 + threadIdx.x; e < E; e += gridDim.x * 256)
    atomicAdd(&h[dst[e] >> 8], 1);
  __syncthreads();
  for (int i = threadIdx.x; i < B; i += 256)
    if (h[i]) atomicAdd(&bcnt[i], h[i]);
}

// -- scan of bucket counts (1 block, 512 threads; B <= 512) --
__global__ __launch_bounds__(512) void bscan_k(const int* __restrict__ bcnt,
                                               int* __restrict__ bstart,
                                               int* __restrict__ bfill,
                                               int* __restrict__ row_start,
                                               int B, int N, int E) {
  __shared__ int sd[512];
  int t = threadIdx.x;
  int v = (t < B) ? bcnt[t] : 0;
  sd[t] = v; __syncthreads();
  for (int off = 1; off < 512; off <<= 1) {
    int x = (t >= off) ? sd[t - off] : 0;
    __syncthreads();
    sd[t] += x;
    __syncthreads();
  }
  if (t < B) {
    int excl = sd[t] - v;
    bstart[t] = excl;
    bfill[t] = excl;
  }
  if (t == 0) { bstart[B] = E; row_start[N] = E; }
}

// -- binning: XCD-affine (bucket%8 == blockIdx%8); packed 4B records --
__global__ __launch_bounds__(256) void bin_k(const int* __restrict__ src,
                                             const int* __restrict__ dst,
                                             int* __restrict__ bfill,
                                             unsigned* __restrict__ ebuf, int E) {
  int x = blockIdx.x & 7;
  int g = blockIdx.x >> 3;
  int G = gridDim.x >> 3;
  for (int e = g * 256 + threadIdx.x; e < E; e += G * 256) {
    int d = dst[e];
    int b = d >> 8;
    if ((b & 7) == x) {
      int pos = atomicAdd(&bfill[b], 1);
      ebuf[pos] = ((unsigned)(d & 255) << 17) | (unsigned)src[e];
    }
  }
}

// -- per-bucket LDS counting sort -> coalesced CSR + row_start + dinv --
__global__ __launch_bounds__(256) void bsort_k(const unsigned* __restrict__ ebuf,
                                               const int* __restrict__ bstart,
                                               int* __restrict__ csr,
                                               int* __restrict__ row_start,
                                               float* __restrict__ dinv, int N) {
  __shared__ int cnt[256];
  __shared__ int sd[256];
  __shared__ int ofs[256];
  __shared__ int sorted[8192];  // mean 4096, sigma ~64 -> cap is +64 sigma
  int b = blockIdx.x, t = threadIdx.x;
  int bs = bstart[b], be = bstart[b + 1];
  int m = be - bs;
  if (m > 8192) m = 8192;  // unreachable safety clamp
  cnt[t] = 0;
  __syncthreads();
  for (int i = t; i < m; i += 256) atomicAdd(&cnt[ebuf[bs + i] >> 17], 1);
  __syncthreads();
  int deg = cnt[t];
  sd[t] = deg; __syncthreads();
  for (int off = 1; off < 256; off <<= 1) {
    int x = (t >= off) ? sd[t - off] : 0;
    __syncthreads();
    sd[t] += x;
    __syncthreads();
  }
  int excl = sd[t] - deg;
  ofs[t] = excl;
  int node = (b << 8) + t;
  if (node < N) {
    row_start[node] = bs + excl;
    dinv[node] = rsqrtf((float)(deg + 1));
  }
  __syncthreads();
  for (int i = t; i < m; i += 256) {
    unsigned r = ebuf[bs + i];
    int d = r >> 17;
    int p = atomicAdd(&ofs[d], 1);
    if (p < 8192) sorted[p] = (int)(r & 0x1FFFFu);
  }
  __syncthreads();
  for (int i = t; i < m; i += 256) csr[bs + i] = sorted[i];
}

// ---------------- GEMM: [M,128] @ [128,NCOL] via 16x16x32 bf16 MFMA ----------------
template <int NCOL, bool INF32, bool OUTF32>
__global__ __launch_bounds__(256) void gemm_k(const void* __restrict__ Ap,
                                              const float* __restrict__ W,
                                              const float* __restrict__ bias,
                                              void* __restrict__ Cp, int M) {
  __shared__ __align__(16) unsigned short Ws[NCOL * 136];  // [n][k], pad k to 136
  int tid = threadIdx.x;
  for (int e = tid; e < 128 * NCOL; e += 256) {
    int k = e / NCOL, n = e % NCOL;
    Ws[n * 136 + k] = f2bf(W[e]);
  }
  __syncthreads();

  int wave = tid >> 6, lane = tid & 63;
  int q = lane >> 4, r = lane & 15;
  const int NT = NCOL / 16;
  int ntile = M >> 4;
  for (int tile = blockIdx.x * 4 + wave; tile < ntile; tile += gridDim.x * 4) {
    int row = tile * 16 + r;
    bf16x8 a[4];
    if (INF32) {
      const float* A = (const float*)Ap + (size_t)row * 128 + q * 8;
#pragma unroll
      for (int kk = 0; kk < 4; kk++) {
        const float4* p = (const float4*)(A + kk * 32);
        float4 f0 = p[0], f1 = p[1];
        bf16x8 tt;
        tt[0] = (short)f2bf(f0.x); tt[1] = (short)f2bf(f0.y);
        tt[2] = (short)f2bf(f0.z); tt[3] = (short)f2bf(f0.w);
        tt[4] = (short)f2bf(f1.x); tt[5] = (short)f2bf(f1.y);
        tt[6] = (short)f2bf(f1.z); tt[7] = (short)f2bf(f1.w);
        a[kk] = tt;
      }
    } else {
      const unsigned short* A = (const unsigned short*)Ap + (size_t)row * 128 + q * 8;
#pragma unroll
      for (int kk = 0; kk < 4; kk++) a[kk] = *(const bf16x8*)(A + kk * 32);
    }
    f32x4 acc[NT];
#pragma unroll
    for (int nt = 0; nt < NT; nt++) { acc[nt][0] = 0.f; acc[nt][1] = 0.f; acc[nt][2] = 0.f; acc[nt][3] = 0.f; }
#pragma unroll
    for (int kk = 0; kk < 4; kk++) {
#pragma unroll
      for (int nt = 0; nt < NT; nt++) {
        bf16x8 bfr = *(const bf16x8*)&Ws[(nt * 16 + r) * 136 + kk * 32 + q * 8];
        acc[nt] = __builtin_amdgcn_mfma_f32_16x16x32_bf16(a[kk], bfr, acc[nt], 0, 0, 0);
      }
    }
#pragma unroll
    for (int nt = 0; nt < NT; nt++) {
#pragma unroll
      for (int rr = 0; rr < 4; rr++) {
        int orow = tile * 16 + q * 4 + rr;
        int ocol = nt * 16 + r;
        if (OUTF32)
          ((float*)Cp)[(size_t)orow * NCOL + ocol] = acc[nt][rr] + bias[ocol];
        else
          ((unsigned short*)Cp)[(size_t)orow * NCOL + ocol] = f2bf(acc[nt][rr]);
      }
    }
  }
}

// ---------------- aggregation: one wave per node, lane = 2 features ----------------
__global__ __launch_bounds__(256) void agg_k(const unsigned* __restrict__ h,
                                             const float* __restrict__ dinv,
                                             const int* __restrict__ row_start,
                                             const int* __restrict__ csr,
                                             const float* __restrict__ bias,
                                             unsigned* __restrict__ out, int N) {
  int lane = threadIdx.x & 63;
  int node = (blockIdx.x * 256 + threadIdx.x) >> 6;
  if (node >= N) return;
  float di = dinv[node];
  unsigned hv = h[(size_t)node * 64 + lane];
  float ax = bf2f((unsigned short)(hv & 0xffffu)) * di;
  float ay = bf2f((unsigned short)(hv >> 16)) * di;
  int beg = row_start[node], end = row_start[node + 1];
  for (int base = beg; base < end; base += 64) {
    int m = end - base; if (m > 64) m = 64;
    int s = 0; float wv = 0.f;
    if (lane < m) { s = csr[base + lane]; wv = dinv[s]; }
    for (int j = 0; j < m; ++j) {
      int sj = __shfl(s, j);
      float wj = __shfl(wv, j);
      unsigned hj = h[(size_t)sj * 64 + lane];
      ax += bf2f((unsigned short)(hj & 0xffffu)) * wj;
      ay += bf2f((unsigned short)(hj >> 16)) * wj;
    }
  }
  float r0 = ax * di + bias[lane * 2];     if (r0 < 0.f) r0 = 0.f;
  float r1 = ay * di + bias[lane * 2 + 1]; if (r1 < 0.f) r1 = 0.f;
  out[(size_t)node * 64 + lane] = (unsigned)f2bf(r0) | ((unsigned)f2bf(r1) << 16);
}

extern "C" void kernel_launch(void* const* d_in, const int* in_sizes, int n_in,
                              void* d_out, int out_size, void* d_ws, size_t ws_size,
                              hipStream_t stream) {
  const float* x  = (const float*)d_in[0];
  const int* ei   = (const int*)d_in[1];
  const float* W1 = (const float*)d_in[2];
  const float* b1 = (const float*)d_in[3];
  const float* W2 = (const float*)d_in[4];
  const float* b2 = (const float*)d_in[5];
  const float* fcW = (const float*)d_in[6];
  const float* fcb = (const float*)d_in[7];
  float* out = (float*)d_out;

  int N = in_sizes[0] / 128;  // 100000
  int E = in_sizes[1] / 2;    // 1600000
  int B = (N + 255) >> 8;     // 391 buckets
  const int* src = ei;
  const int* dst = ei + E;

  char* w = (char*)d_ws;
  auto alloc = [&](size_t b) { char* p = w; w += (b + 255) & ~(size_t)255; return p; };
  float* dinv      = (float*)alloc((size_t)N * 4);
  int*   row_start = (int*)alloc((size_t)(N + 1) * 4);
  int*   bcnt      = (int*)alloc((size_t)(B + 1) * 4);
  int*   bstart    = (int*)alloc((size_t)(B + 1) * 4);
  int*   bfill     = (int*)alloc((size_t)(B + 1) * 4);
  unsigned* ebuf   = (unsigned*)alloc((size_t)E * 4);
  int*   csr       = (int*)alloc((size_t)E * 4);
  unsigned short* bufA = (unsigned short*)alloc((size_t)N * 128 * 2);
  unsigned short* bufB = (unsigned short*)alloc((size_t)N * 128 * 2);

  hipMemsetAsync(bcnt, 0, (size_t)(B + 1) * 4, stream);

  bhist_k<<<512, 256, 0, stream>>>(dst, bcnt, E, B);
  bscan_k<<<1, 512, 0, stream>>>(bcnt, bstart, bfill, row_start, B, N, E);
  bin_k<<<1024, 256, 0, stream>>>(src, dst, bfill, ebuf, E);
  bsort_k<<<B, 256, 0, stream>>>(ebuf, bstart, csr, row_start, dinv, N);

  // layer 1: h1 = x @ W1   (fp32 in, bf16 out)
  gemm_k<128, true, false><<<512, 256, 0, stream>>>((const void*)x, W1, nullptr, (void*)bufA, N);
  // agg1: a1 = relu(norm-agg(h1) + b1)  (bf16)
  agg_k<<<(N + 3) / 4, 256, 0, stream>>>((const unsigned*)bufA, dinv, row_start, csr, b1,
                                         (unsigned*)bufB, N);
  // layer 2: h2 = a1 @ W2
  gemm_k<128, false, false><<<512, 256, 0, stream>>>((const void*)bufB, W2, nullptr, (void*)bufA, N);
  // agg2: a2 = relu(norm-agg(h2) + b2)
  agg_k<<<(N + 3) / 4, 256, 0, stream>>>((const unsigned*)bufA, dinv, row_start, csr, b2,
                                         (unsigned*)bufB, N);
  // fc: out = a2 @ fcW + fcb  (fp32 out)
  gemm_k<64, false, true><<<512, 256, 0, stream>>>((const void*)bufB, fcW, fcb, (void*)out, N);
}

// Round 3
// 422.259 us; speedup vs baseline: 3.6409x; 3.6409x over previous
//
#include <hip/hip_runtime.h>

typedef __attribute__((ext_vector_type(8))) short bf16x8;
typedef __attribute__((ext_vector_type(4))) float f32x4;

__device__ __forceinline__ unsigned short f2bf(float x) {
  union { float f; unsigned u; } v; v.f = x;
  return (unsigned short)((v.u + 0x7fffu + ((v.u >> 16) & 1u)) >> 16);
}
__device__ __forceinline__ float bf2f(unsigned short h) {
  union { unsigned u; float f; } v; v.u = ((unsigned)h) << 16; return v.f;
}

// ================= CSR build: two-level counting sort by dst =================
// Bucket = dst >> 8 (256 nodes/bucket). Record = (dst&255)<<17 | src (25 bits).
// Global bucket counters padded to 1 per 64B line (stride 16 ints) to avoid
// L2-slice atomic serialization.

__global__ __launch_bounds__(256) void bhist_k(const int* __restrict__ dst,
                                               int* __restrict__ bcnt, int E, int B) {
  __shared__ int h[512];
  for (int i = threadIdx.x; i < B; i += 256) h[i] = 0;
  __syncthreads();
  for (int e = blockIdx.x * 256 + threadIdx.x; e < E; e += gridDim.x * 256)
    atomicAdd(&h[dst[e] >> 8], 1);
  __syncthreads();
  for (int i = threadIdx.x; i < B; i += 256)
    if (h[i]) atomicAdd(&bcnt[i * 16], h[i]);
}

__global__ __launch_bounds__(512) void bscan_k(const int* __restrict__ bcnt,
                                               int* __restrict__ bstart,
                                               int* __restrict__ bfill,
                                               int* __restrict__ row_start,
                                               int B, int N, int E) {
  __shared__ int sd[512];
  int t = threadIdx.x;
  int v = (t < B) ? bcnt[t * 16] : 0;
  sd[t] = v; __syncthreads();
  for (int off = 1; off < 512; off <<= 1) {
    int x = (t >= off) ? sd[t - off] : 0;
    __syncthreads();
    sd[t] += x;
    __syncthreads();
  }
  if (t < B) {
    int excl = sd[t] - v;
    bstart[t] = excl;
    bfill[t * 16] = excl;  // padded running cursor
  }
  if (t == 0) { bstart[B] = E; row_start[N] = E; }
}

// -- binning: per-block LDS hist + one reservation atomic per (block,bucket) --
__global__ __launch_bounds__(256) void bin_k(const int* __restrict__ src,
                                             const int* __restrict__ dst,
                                             int* __restrict__ bfill,
                                             unsigned* __restrict__ ebuf, int E, int B) {
  __shared__ int hist[512];
  __shared__ int base[512];
  int t = threadIdx.x;
  int chunk = (E + gridDim.x - 1) / gridDim.x;
  int e0 = blockIdx.x * chunk;
  int e1 = e0 + chunk; if (e1 > E) e1 = E;
  for (int i = t; i < B; i += 256) hist[i] = 0;
  __syncthreads();
  for (int e = e0 + t; e < e1; e += 256) atomicAdd(&hist[dst[e] >> 8], 1);
  __syncthreads();
  for (int i = t; i < B; i += 256) {
    int c = hist[i];
    base[i] = c ? atomicAdd(&bfill[i * 16], c) : 0;
  }
  __syncthreads();
  for (int e = e0 + t; e < e1; e += 256) {
    int d = dst[e];
    int b = d >> 8;
    int pos = atomicAdd(&base[b], 1);  // LDS atomic
    ebuf[pos] = ((unsigned)(d & 255) << 17) | (unsigned)src[e];
  }
}

// -- per-bucket LDS counting sort -> coalesced CSR + row_start + dinv --
__global__ __launch_bounds__(256) void bsort_k(const unsigned* __restrict__ ebuf,
                                               const int* __restrict__ bstart,
                                               int* __restrict__ csr,
                                               int* __restrict__ row_start,
                                               float* __restrict__ dinv, int N) {
  __shared__ int cnt[256];
  __shared__ int sd[256];
  __shared__ int ofs[256];
  __shared__ int sorted[8192];  // mean 4096, sigma ~64 -> cap is +64 sigma
  int b = blockIdx.x, t = threadIdx.x;
  int bs = bstart[b], be = bstart[b + 1];
  int m = be - bs;
  if (m > 8192) m = 8192;  // unreachable safety clamp
  cnt[t] = 0;
  __syncthreads();
  for (int i = t; i < m; i += 256) atomicAdd(&cnt[ebuf[bs + i] >> 17], 1);
  __syncthreads();
  int deg = cnt[t];
  sd[t] = deg; __syncthreads();
  for (int off = 1; off < 256; off <<= 1) {
    int x = (t >= off) ? sd[t - off] : 0;
    __syncthreads();
    sd[t] += x;
    __syncthreads();
  }
  int excl = sd[t] - deg;
  ofs[t] = excl;
  int node = (b << 8) + t;
  if (node < N) {
    row_start[node] = bs + excl;
    dinv[node] = rsqrtf((float)(deg + 1));
  }
  __syncthreads();
  for (int i = t; i < m; i += 256) {
    unsigned r = ebuf[bs + i];
    int d = r >> 17;
    int p = atomicAdd(&ofs[d], 1);
    if (p < 8192) sorted[p] = (int)(r & 0x1FFFFu);
  }
  __syncthreads();
  for (int i = t; i < m; i += 256) csr[bs + i] = sorted[i];
}

// ---------------- GEMM: [M,128] @ [128,NCOL] via 16x16x32 bf16 MFMA ----------------
template <int NCOL, bool INF32, bool OUTF32>
__global__ __launch_bounds__(256) void gemm_k(const void* __restrict__ Ap,
                                              const float* __restrict__ W,
                                              const float* __restrict__ bias,
                                              void* __restrict__ Cp, int M) {
  __shared__ __align__(16) unsigned short Ws[NCOL * 136];  // [n][k], pad k to 136
  int tid = threadIdx.x;
  for (int e = tid; e < 128 * NCOL; e += 256) {
    int k = e / NCOL, n = e % NCOL;
    Ws[n * 136 + k] = f2bf(W[e]);
  }
  __syncthreads();

  int wave = tid >> 6, lane = tid & 63;
  int q = lane >> 4, r = lane & 15;
  const int NT = NCOL / 16;
  int ntile = M >> 4;
  for (int tile = blockIdx.x * 4 + wave; tile < ntile; tile += gridDim.x * 4) {
    int row = tile * 16 + r;
    bf16x8 a[4];
    if (INF32) {
      const float* A = (const float*)Ap + (size_t)row * 128 + q * 8;
#pragma unroll
      for (int kk = 0; kk < 4; kk++) {
        const float4* p = (const float4*)(A + kk * 32);
        float4 f0 = p[0], f1 = p[1];
        bf16x8 tt;
        tt[0] = (short)f2bf(f0.x); tt[1] = (short)f2bf(f0.y);
        tt[2] = (short)f2bf(f0.z); tt[3] = (short)f2bf(f0.w);
        tt[4] = (short)f2bf(f1.x); tt[5] = (short)f2bf(f1.y);
        tt[6] = (short)f2bf(f1.z); tt[7] = (short)f2bf(f1.w);
        a[kk] = tt;
      }
    } else {
      const unsigned short* A = (const unsigned short*)Ap + (size_t)row * 128 + q * 8;
#pragma unroll
      for (int kk = 0; kk < 4; kk++) a[kk] = *(const bf16x8*)(A + kk * 32);
    }
    f32x4 acc[NT];
#pragma unroll
    for (int nt = 0; nt < NT; nt++) { acc[nt][0] = 0.f; acc[nt][1] = 0.f; acc[nt][2] = 0.f; acc[nt][3] = 0.f; }
#pragma unroll
    for (int kk = 0; kk < 4; kk++) {
#pragma unroll
      for (int nt = 0; nt < NT; nt++) {
        bf16x8 bfr = *(const bf16x8*)&Ws[(nt * 16 + r) * 136 + kk * 32 + q * 8];
        acc[nt] = __builtin_amdgcn_mfma_f32_16x16x32_bf16(a[kk], bfr, acc[nt], 0, 0, 0);
      }
    }
#pragma unroll
    for (int nt = 0; nt < NT; nt++) {
#pragma unroll
      for (int rr = 0; rr < 4; rr++) {
        int orow = tile * 16 + q * 4 + rr;
        int ocol = nt * 16 + r;
        if (OUTF32)
          ((float*)Cp)[(size_t)orow * NCOL + ocol] = acc[nt][rr] + bias[ocol];
        else
          ((unsigned short*)Cp)[(size_t)orow * NCOL + ocol] = f2bf(acc[nt][rr]);
      }
    }
  }
}

// ---------------- aggregation: one wave per node, lane = 2 features ----------------
__global__ __launch_bounds__(256) void agg_k(const unsigned* __restrict__ h,
                                             const float* __restrict__ dinv,
                                             const int* __restrict__ row_start,
                                             const int* __restrict__ csr,
                                             const float* __restrict__ bias,
                                             unsigned* __restrict__ out, int N) {
  int lane = threadIdx.x & 63;
  int node = (blockIdx.x * 256 + threadIdx.x) >> 6;
  if (node >= N) return;
  float di = dinv[node];
  unsigned hv = h[(size_t)node * 64 + lane];
  float ax = bf2f((unsigned short)(hv & 0xffffu)) * di;
  float ay = bf2f((unsigned short)(hv >> 16)) * di;
  int beg = row_start[node], end = row_start[node + 1];
  for (int base = beg; base < end; base += 64) {
    int m = end - base; if (m > 64) m = 64;
    int s = 0; float wv = 0.f;
    if (lane < m) { s = csr[base + lane]; wv = dinv[s]; }
    for (int j = 0; j < m; ++j) {
      int sj = __shfl(s, j);
      float wj = __shfl(wv, j);
      unsigned hj = h[(size_t)sj * 64 + lane];
      ax += bf2f((unsigned short)(hj & 0xffffu)) * wj;
      ay += bf2f((unsigned short)(hj >> 16)) * wj;
    }
  }
  float r0 = ax * di + bias[lane * 2];     if (r0 < 0.f) r0 = 0.f;
  float r1 = ay * di + bias[lane * 2 + 1]; if (r1 < 0.f) r1 = 0.f;
  out[(size_t)node * 64 + lane] = (unsigned)f2bf(r0) | ((unsigned)f2bf(r1) << 16);
}

extern "C" void kernel_launch(void* const* d_in, const int* in_sizes, int n_in,
                              void* d_out, int out_size, void* d_ws, size_t ws_size,
                              hipStream_t stream) {
  const float* x  = (const float*)d_in[0];
  const int* ei   = (const int*)d_in[1];
  const float* W1 = (const float*)d_in[2];
  const float* b1 = (const float*)d_in[3];
  const float* W2 = (const float*)d_in[4];
  const float* b2 = (const float*)d_in[5];
  const float* fcW = (const float*)d_in[6];
  const float* fcb = (const float*)d_in[7];
  float* out = (float*)d_out;

  int N = in_sizes[0] / 128;  // 100000
  int E = in_sizes[1] / 2;    // 1600000
  int B = (N + 255) >> 8;     // 391 buckets
  const int* src = ei;
  const int* dst = ei + E;

  char* w = (char*)d_ws;
  auto alloc = [&](size_t b) { char* p = w; w += (b + 255) & ~(size_t)255; return p; };
  float* dinv      = (float*)alloc((size_t)N * 4);
  int*   row_start = (int*)alloc((size_t)(N + 1) * 4);
  int*   bcnt      = (int*)alloc((size_t)(B + 1) * 64);  // stride-16 padded
  int*   bstart    = (int*)alloc((size_t)(B + 1) * 4);
  int*   bfill     = (int*)alloc((size_t)(B + 1) * 64);  // stride-16 padded
  unsigned* ebuf   = (unsigned*)alloc((size_t)E * 4);
  int*   csr       = (int*)alloc((size_t)E * 4);
  unsigned short* bufA = (unsigned short*)alloc((size_t)N * 128 * 2);
  unsigned short* bufB = (unsigned short*)alloc((size_t)N * 128 * 2);

  hipMemsetAsync(bcnt, 0, (size_t)(B + 1) * 64, stream);

  bhist_k<<<256, 256, 0, stream>>>(dst, bcnt, E, B);
  bscan_k<<<1, 512, 0, stream>>>(bcnt, bstart, bfill, row_start, B, N, E);
  bin_k<<<256, 256, 0, stream>>>(src, dst, bfill, ebuf, E, B);
  bsort_k<<<B, 256, 0, stream>>>(ebuf, bstart, csr, row_start, dinv, N);

  // layer 1: h1 = x @ W1   (fp32 in, bf16 out)
  gemm_k<128, true, false><<<512, 256, 0, stream>>>((const void*)x, W1, nullptr, (void*)bufA, N);
  // agg1: a1 = relu(norm-agg(h1) + b1)  (bf16)
  agg_k<<<(N + 3) / 4, 256, 0, stream>>>((const unsigned*)bufA, dinv, row_start, csr, b1,
                                         (unsigned*)bufB, N);
  // layer 2: h2 = a1 @ W2
  gemm_k<128, false, false><<<512, 256, 0, stream>>>((const void*)bufB, W2, nullptr, (void*)bufA, N);
  // agg2: a2 = relu(norm-agg(h2) + b2)
  agg_k<<<(N + 3) / 4, 256, 0, stream>>>((const unsigned*)bufA, dinv, row_start, csr, b2,
                                         (unsigned*)bufB, N);
  // fc: out = a2 @ fcW + fcb  (fp32 out)
  gemm_k<64, false, true><<<512, 256, 0, stream>>>((const void*)bufB, fcW, fcb, (void*)out, N);
}

// Round 4
// 336.758 us; speedup vs baseline: 4.5653x; 1.2539x over previous
//
#include <hip/hip_runtime.h>

typedef __attribute__((ext_vector_type(8))) short bf16x8;
typedef __attribute__((ext_vector_type(4))) float f32x4;

__device__ __forceinline__ unsigned short f2bf(float x) {
  union { float f; unsigned u; } v; v.f = x;
  return (unsigned short)((v.u + 0x7fffu + ((v.u >> 16) & 1u)) >> 16);
}
__device__ __forceinline__ float bf2f(unsigned short h) {
  union { unsigned u; float f; } v; v.u = ((unsigned)h) << 16; return v.f;
}

// ================= CSR build: two-level counting sort by dst =================
// Bucket = dst >> 8 (256 nodes/bucket). Record = (dst&255)<<17 | src (25 bits).

__global__ __launch_bounds__(256) void bhist_k(const int* __restrict__ dst,
                                               int* __restrict__ bcnt, int E, int B) {
  __shared__ int h[512];
  for (int i = threadIdx.x; i < B; i += 256) h[i] = 0;
  __syncthreads();
  for (int e = blockIdx.x * 256 + threadIdx.x; e < E; e += gridDim.x * 256)
    atomicAdd(&h[dst[e] >> 8], 1);
  __syncthreads();
  for (int i = threadIdx.x; i < B; i += 256)
    if (h[i]) atomicAdd(&bcnt[i * 16], h[i]);
}

__global__ __launch_bounds__(512) void bscan_k(const int* __restrict__ bcnt,
                                               int* __restrict__ bstart,
                                               int* __restrict__ bfill,
                                               int* __restrict__ row_start,
                                               int B, int N, int E) {
  __shared__ int sd[512];
  int t = threadIdx.x;
  int v = (t < B) ? bcnt[t * 16] : 0;
  sd[t] = v; __syncthreads();
  for (int off = 1; off < 512; off <<= 1) {
    int x = (t >= off) ? sd[t - off] : 0;
    __syncthreads();
    sd[t] += x;
    __syncthreads();
  }
  if (t < B) {
    int excl = sd[t] - v;
    bstart[t] = excl;
    bfill[t * 16] = excl;  // padded running cursor
  }
  if (t == 0) { bstart[B] = E; row_start[N] = E; }
}

// -- binning: per-block LDS hist + one reservation atomic per (block,bucket) --
__global__ __launch_bounds__(256) void bin_k(const int* __restrict__ src,
                                             const int* __restrict__ dst,
                                             int* __restrict__ bfill,
                                             unsigned* __restrict__ ebuf, int E, int B) {
  __shared__ int hist[512];
  __shared__ int base[512];
  int t = threadIdx.x;
  int chunk = (E + gridDim.x - 1) / gridDim.x;
  int e0 = blockIdx.x * chunk;
  int e1 = e0 + chunk; if (e1 > E) e1 = E;
  for (int i = t; i < B; i += 256) hist[i] = 0;
  __syncthreads();
  for (int e = e0 + t; e < e1; e += 256) atomicAdd(&hist[dst[e] >> 8], 1);
  __syncthreads();
  for (int i = t; i < B; i += 256) {
    int c = hist[i];
    base[i] = c ? atomicAdd(&bfill[i * 16], c) : 0;
  }
  __syncthreads();
  for (int e = e0 + t; e < e1; e += 256) {
    int d = dst[e];
    int b = d >> 8;
    int pos = atomicAdd(&base[b], 1);  // LDS atomic
    ebuf[pos] = ((unsigned)(d & 255) << 17) | (unsigned)src[e];
  }
}

// -- per-bucket LDS counting sort -> coalesced CSR + row_start + dinv --
__global__ __launch_bounds__(256) void bsort_k(const unsigned* __restrict__ ebuf,
                                               const int* __restrict__ bstart,
                                               int* __restrict__ csr,
                                               int* __restrict__ row_start,
                                               float* __restrict__ dinv, int N) {
  __shared__ int cnt[256];
  __shared__ int sd[256];
  __shared__ int ofs[256];
  __shared__ int sorted[8192];  // mean 4096, sigma ~64 -> cap is +64 sigma
  int b = blockIdx.x, t = threadIdx.x;
  int bs = bstart[b], be = bstart[b + 1];
  int m = be - bs;
  if (m > 8192) m = 8192;  // unreachable safety clamp
  cnt[t] = 0;
  __syncthreads();
  for (int i = t; i < m; i += 256) atomicAdd(&cnt[ebuf[bs + i] >> 17], 1);
  __syncthreads();
  int deg = cnt[t];
  sd[t] = deg; __syncthreads();
  for (int off = 1; off < 256; off <<= 1) {
    int x = (t >= off) ? sd[t - off] : 0;
    __syncthreads();
    sd[t] += x;
    __syncthreads();
  }
  int excl = sd[t] - deg;
  ofs[t] = excl;
  int node = (b << 8) + t;
  if (node < N) {
    row_start[node] = bs + excl;
    dinv[node] = rsqrtf((float)(deg + 1));
  }
  __syncthreads();
  for (int i = t; i < m; i += 256) {
    unsigned r = ebuf[bs + i];
    int d = r >> 17;
    int p = atomicAdd(&ofs[d], 1);
    if (p < 8192) sorted[p] = (int)(r & 0x1FFFFu);
  }
  __syncthreads();
  for (int i = t; i < m; i += 256) csr[bs + i] = sorted[i];
}

// ---------------- GEMM: [M,128] @ [128,NCOL] via 16x16x32 bf16 MFMA ----------------
template <int NCOL, bool INF32, bool OUTF32>
__global__ __launch_bounds__(256) void gemm_k(const void* __restrict__ Ap,
                                              const float* __restrict__ W,
                                              const float* __restrict__ bias,
                                              void* __restrict__ Cp, int M) {
  __shared__ __align__(16) unsigned short Ws[NCOL * 136];  // [n][k], pad k to 136
  int tid = threadIdx.x;
  for (int e = tid; e < 128 * NCOL; e += 256) {
    int k = e / NCOL, n = e % NCOL;
    Ws[n * 136 + k] = f2bf(W[e]);
  }
  __syncthreads();

  int wave = tid >> 6, lane = tid & 63;
  int q = lane >> 4, r = lane & 15;
  const int NT = NCOL / 16;
  int ntile = M >> 4;
  for (int tile = blockIdx.x * 4 + wave; tile < ntile; tile += gridDim.x * 4) {
    int row = tile * 16 + r;
    bf16x8 a[4];
    if (INF32) {
      const float* A = (const float*)Ap + (size_t)row * 128 + q * 8;
#pragma unroll
      for (int kk = 0; kk < 4; kk++) {
        const float4* p = (const float4*)(A + kk * 32);
        float4 f0 = p[0], f1 = p[1];
        bf16x8 tt;
        tt[0] = (short)f2bf(f0.x); tt[1] = (short)f2bf(f0.y);
        tt[2] = (short)f2bf(f0.z); tt[3] = (short)f2bf(f0.w);
        tt[4] = (short)f2bf(f1.x); tt[5] = (short)f2bf(f1.y);
        tt[6] = (short)f2bf(f1.z); tt[7] = (short)f2bf(f1.w);
        a[kk] = tt;
      }
    } else {
      const unsigned short* A = (const unsigned short*)Ap + (size_t)row * 128 + q * 8;
#pragma unroll
      for (int kk = 0; kk < 4; kk++) a[kk] = *(const bf16x8*)(A + kk * 32);
    }
    f32x4 acc[NT];
#pragma unroll
    for (int nt = 0; nt < NT; nt++) { acc[nt][0] = 0.f; acc[nt][1] = 0.f; acc[nt][2] = 0.f; acc[nt][3] = 0.f; }
#pragma unroll
    for (int kk = 0; kk < 4; kk++) {
#pragma unroll
      for (int nt = 0; nt < NT; nt++) {
        bf16x8 bfr = *(const bf16x8*)&Ws[(nt * 16 + r) * 136 + kk * 32 + q * 8];
        acc[nt] = __builtin_amdgcn_mfma_f32_16x16x32_bf16(a[kk], bfr, acc[nt], 0, 0, 0);
      }
    }
#pragma unroll
    for (int nt = 0; nt < NT; nt++) {
#pragma unroll
      for (int rr = 0; rr < 4; rr++) {
        int orow = tile * 16 + q * 4 + rr;
        int ocol = nt * 16 + r;
        if (OUTF32)
          ((float*)Cp)[(size_t)orow * NCOL + ocol] = acc[nt][rr] + bias[ocol];
        else
          ((unsigned short*)Cp)[(size_t)orow * NCOL + ocol] = f2bf(acc[nt][rr]);
      }
    }
  }
}

// ---------------- aggregation v2: one wave per node, 4 edges in flight ----------------
// lane = (g = lane>>4, r = lane&15). Group g handles edge-slot jb+g; lane loads
// 16B (8 feats) of that edge's source row. Self-loop folded in as virtual edge -1
// with weight dinv[node]. Epilogue: shfl_xor(16,32) cross-group reduce, bias+relu,
// 16-lane 256B row store.
__global__ __launch_bounds__(256) void agg_k(const unsigned short* __restrict__ h,
                                             const float* __restrict__ dinv,
                                             const int* __restrict__ row_start,
                                             const int* __restrict__ csr,
                                             const float* __restrict__ bias,
                                             unsigned short* __restrict__ out, int N) {
  int lane = threadIdx.x & 63;
  int node = (blockIdx.x * 256 + threadIdx.x) >> 6;
  if (node >= N) return;
  int g = lane >> 4, r = lane & 15;
  float di = dinv[node];
  int beg = row_start[node];
  int deg = row_start[node + 1] - beg;

  float acc[8];
#pragma unroll
  for (int i = 0; i < 8; i++) acc[i] = 0.f;

  for (int base = -1; base < deg; base += 64) {
    int idx = base + lane;
    int s = node; float wv = 0.f;
    if (idx < 0) { wv = di; }                       // virtual self edge
    else if (idx < deg) { s = csr[beg + idx]; wv = dinv[s]; }
    int cntv = deg - base; if (cntv > 64) cntv = 64;  // valid slots this chunk
    for (int j = 0; j < cntv; j += 4) {
      int lanesel = j + g;                          // <= 63 always (j <= 60)
      int sj = __shfl(s, lanesel);
      float wj = __shfl(wv, lanesel);
      bf16x8 hv = *(const bf16x8*)(h + (size_t)sj * 128 + r * 8);
#pragma unroll
      for (int i = 0; i < 8; i++)
        acc[i] += bf2f((unsigned short)hv[i]) * wj;
    }
  }

  // reduce across the 4 groups (lanes differing in bits 4..5)
#pragma unroll
  for (int i = 0; i < 8; i++) {
    acc[i] += __shfl_xor(acc[i], 16);
    acc[i] += __shfl_xor(acc[i], 32);
  }

  if (g == 0) {
    bf16x8 t;
#pragma unroll
    for (int i = 0; i < 8; i++) {
      float v = acc[i] * di + bias[r * 8 + i];
      if (v < 0.f) v = 0.f;
      t[i] = (short)f2bf(v);
    }
    *(bf16x8*)(out + (size_t)node * 128 + r * 8) = t;
  }
}

extern "C" void kernel_launch(void* const* d_in, const int* in_sizes, int n_in,
                              void* d_out, int out_size, void* d_ws, size_t ws_size,
                              hipStream_t stream) {
  const float* x  = (const float*)d_in[0];
  const int* ei   = (const int*)d_in[1];
  const float* W1 = (const float*)d_in[2];
  const float* b1 = (const float*)d_in[3];
  const float* W2 = (const float*)d_in[4];
  const float* b2 = (const float*)d_in[5];
  const float* fcW = (const float*)d_in[6];
  const float* fcb = (const float*)d_in[7];
  float* out = (float*)d_out;

  int N = in_sizes[0] / 128;  // 100000
  int E = in_sizes[1] / 2;    // 1600000
  int B = (N + 255) >> 8;     // 391 buckets
  const int* src = ei;
  const int* dst = ei + E;

  char* w = (char*)d_ws;
  auto alloc = [&](size_t b) { char* p = w; w += (b + 255) & ~(size_t)255; return p; };
  float* dinv      = (float*)alloc((size_t)N * 4);
  int*   row_start = (int*)alloc((size_t)(N + 1) * 4);
  int*   bcnt      = (int*)alloc((size_t)(B + 1) * 64);  // stride-16 padded
  int*   bstart    = (int*)alloc((size_t)(B + 1) * 4);
  int*   bfill     = (int*)alloc((size_t)(B + 1) * 64);  // stride-16 padded
  unsigned* ebuf   = (unsigned*)alloc((size_t)E * 4);
  int*   csr       = (int*)alloc((size_t)E * 4);
  unsigned short* bufA = (unsigned short*)alloc((size_t)N * 128 * 2);
  unsigned short* bufB = (unsigned short*)alloc((size_t)N * 128 * 2);

  hipMemsetAsync(bcnt, 0, (size_t)(B + 1) * 64, stream);

  bhist_k<<<256, 256, 0, stream>>>(dst, bcnt, E, B);
  bscan_k<<<1, 512, 0, stream>>>(bcnt, bstart, bfill, row_start, B, N, E);
  bin_k<<<256, 256, 0, stream>>>(src, dst, bfill, ebuf, E, B);
  bsort_k<<<B, 256, 0, stream>>>(ebuf, bstart, csr, row_start, dinv, N);

  // layer 1: h1 = x @ W1   (fp32 in, bf16 out)
  gemm_k<128, true, false><<<512, 256, 0, stream>>>((const void*)x, W1, nullptr, (void*)bufA, N);
  // agg1: a1 = relu(norm-agg(h1) + b1)  (bf16)
  agg_k<<<(N + 3) / 4, 256, 0, stream>>>(bufA, dinv, row_start, csr, b1, bufB, N);
  // layer 2: h2 = a1 @ W2
  gemm_k<128, false, false><<<512, 256, 0, stream>>>((const void*)bufB, W2, nullptr, (void*)bufA, N);
  // agg2: a2 = relu(norm-agg(h2) + b2)
  agg_k<<<(N + 3) / 4, 256, 0, stream>>>(bufA, dinv, row_start, csr, b2, bufB, N);
  // fc: out = a2 @ fcW + fcb  (fp32 out)
  gemm_k<64, false, true><<<512, 256, 0, stream>>>((const void*)bufB, fcW, fcb, (void*)out, N);
}